// Round 10
// baseline (150.494 us; speedup 1.0000x reference)
//
#include <hip/hip_runtime.h>

// TensorProduct: out[z, o*U+u] = sum_{p: idx_out[p]==o} coeffs[p] * x0[z, idx0[p]*U+u] * x1[z, idx1[p]*U+u]
// Z=16384, U=128, NSEG=(32,8,32), P=128, all f32. Measured HBM ~436 MB -> ~75-85 us floor.
// R5/R9 persistent dbuf: regressed twice (store-drain bubble at per-tile barrier) -> abandoned.
// R10 = R8 one-shot base (109 us) with x1 moved off the LDS pipe: x1 read per-term via
// global_load_dwordx4 (L1-resident 4 KB/z-row; vmcnt) while x0 stays in LDS (lgkmcnt).
// Separate counters/pipes -> no R5 lgkmcnt-mixing hazard. LDS traffic/z halves;
// LDS/block 22->17.2 KB. Depth-1 prefetch on meta and x1.

#define Z_DIM 16384
#define U_DIM 128
#define NSEG0 32
#define NSEG1 8
#define NSEG2 32
#define P_DIM 128
#define BLK   512

#define X0_FLOATS (NSEG0 * U_DIM)   // 4096 floats (16 KB)
#define X1_FLOATS (NSEG1 * U_DIM)   // 1024 floats (4 KB)

// blob layout (ints): [0..32] seg offsets, [33..39] pad, [40..295] meta int2[128], [296..303] pad
#define META_BASE 40
#define BLOB_INTS 304                // 1216 B = 76 * 16 B

typedef float f32x4 __attribute__((ext_vector_type(4)));

// ---------- setup: group the P terms by output segment into the ws blob ----------
__global__ __launch_bounds__(128) void tp_setup(
    const float* __restrict__ coeffs,
    const int* __restrict__ idx0,
    const int* __restrict__ idx1,
    const int* __restrict__ idx_out,
    int* __restrict__ blob)
{
    __shared__ int s_cnt[NSEG2];
    __shared__ int s_off[NSEG2 + 1];
    const int t = threadIdx.x;            // exactly P_DIM threads
    if (t < NSEG2) s_cnt[t] = 0;
    __syncthreads();
    const int o = idx_out[t];
    const int r = atomicAdd(&s_cnt[o], 1);
    __syncthreads();
    if (t == 0) {
        int sum = 0;
        for (int i = 0; i < NSEG2; ++i) { s_off[i] = sum; sum += s_cnt[i]; }
        s_off[NSEG2] = sum;
    }
    __syncthreads();
    // byte offsets within a z-slice: i0*512 <= 15872, i1*512 <= 3584 (fit 16b each)
    const int d = s_off[o] + r;
    int2* meta = reinterpret_cast<int2*>(blob + META_BASE);
    meta[d] = make_int2((idx0[t] * (U_DIM * 4)) | ((idx1[t] * (U_DIM * 4)) << 16),
                        __float_as_int(coeffs[t]));
    if (t <= NSEG2) blob[t] = s_off[t];
    if (t >= 33 && t < META_BASE) blob[t] = 0;                       // pad
    if (t >= 296 && t < BLOB_INTS) blob[t] = 0;                      // tail pad
}

// ---------- main: one z-row per block (R8 skeleton) ----------
__global__ __launch_bounds__(BLK, 8) void tp_kernel(
    const float* __restrict__ x0,
    const float* __restrict__ x1,
    const int* __restrict__ blob_g,
    float* __restrict__ out)
{
    __shared__ float s_x0[X0_FLOATS];     // 16 KB
    __shared__ int   s_blob[BLOB_INTS];   // ~1.2 KB  -> 17.2 KB total

    const int t = threadIdx.x;
    const size_t z = (size_t)blockIdx.x;

    // --- stage x0 row + blob: async global->LDS, linear, 16 B/lane ---
    {
        const float4* g0 = reinterpret_cast<const float4*>(x0 + z * (size_t)X0_FLOATS);
        const float4* gb = reinterpret_cast<const float4*>(blob_g);
        float4* l0 = reinterpret_cast<float4*>(s_x0);
        float4* lb = reinterpret_cast<float4*>(s_blob);
        #pragma unroll
        for (int i = 0; i < (X0_FLOATS / 4) / BLK; ++i)   // 2 iters
            __builtin_amdgcn_global_load_lds(
                (const __attribute__((address_space(1))) void*)(g0 + i * BLK + t),
                (__attribute__((address_space(3))) void*)(l0 + i * BLK + t),
                16, 0, 0);
        if (t < BLOB_INTS / 4)                             // 76 lanes
            __builtin_amdgcn_global_load_lds(
                (const __attribute__((address_space(1))) void*)(gb + t),
                (__attribute__((address_space(3))) void*)(lb + t),
                16, 0, 0);
    }
    __syncthreads();   // drains vmcnt; LDS tile + blob ready

    // --- compute: 8 waves x 4 segments; each 32-lane half owns 2 segments ---
    const int w  = t >> 6;                // wave 0..7
    const int h  = (t >> 5) & 1;          // lane half
    const int uq = t & 31;                // float4 column

    const int seg0 = 4 * w + 2 * h;       // this half's first segment
    const char* x0base = reinterpret_cast<const char*>(s_x0 + uq * 4);
    const char* x1base = reinterpret_cast<const char*>(x1 + z * (size_t)X1_FLOATS) + uq * 16;
    const int2* s_meta = reinterpret_cast<const int2*>(s_blob + META_BASE);
    float* orow = out + z * (NSEG2 * U_DIM) + uq * 4;

    const int b = s_blob[seg0];           // half-divergent bounds (2-valued), benign
    const int m = s_blob[seg0 + 1];
    const int e = s_blob[seg0 + 2];

    int sb = b;
    #pragma unroll
    for (int oo = 0; oo < 2; ++oo) {
        const int se = (oo == 0) ? m : e;
        f32x4 acc = (f32x4)0.f;
        int2 mt = s_meta[sb];             // s_meta[128] is zeroed pad, in-bounds
        f32x4 v  = *reinterpret_cast<const f32x4*>(x1base + ((unsigned)mt.x >> 16)); // prefetched x1
        for (int k = sb; k < se; ++k) {
            const int2 mn = s_meta[k + 1];                                            // meta prefetch
            const f32x4 vn = *reinterpret_cast<const f32x4*>(x1base + ((unsigned)mn.x >> 16)); // x1 prefetch
            const float c = __int_as_float(mt.y);
            const f32x4 a = *reinterpret_cast<const f32x4*>(x0base + (mt.x & 0xffff));  // LDS
            acc += a * v * c;             // contracts to v_fma
            mt = mn; v = vn;
        }
        __builtin_nontemporal_store(acc,
            reinterpret_cast<f32x4*>(orow + (seg0 + oo) * U_DIM));
        sb = se;
    }
}

extern "C" void kernel_launch(void* const* d_in, const int* in_sizes, int n_in,
                              void* d_out, int out_size, void* d_ws, size_t ws_size,
                              hipStream_t stream) {
    const float* x0      = (const float*)d_in[0];
    const float* x1      = (const float*)d_in[1];
    const float* coeffs  = (const float*)d_in[2];
    const int*   idx0    = (const int*)d_in[3];
    const int*   idx1    = (const int*)d_in[4];
    const int*   idx_out = (const int*)d_in[5];
    float* out = (float*)d_out;

    int* blob = (int*)d_ws;   // BLOB_INTS ints, 16B-aligned

    tp_setup<<<1, P_DIM, 0, stream>>>(coeffs, idx0, idx1, idx_out, blob);
    tp_kernel<<<Z_DIM, BLK, 0, stream>>>(x0, x1, blob, out);
}

// Round 11
// 111.881 us; speedup vs baseline: 1.3451x; 1.3451x over previous
//
#include <hip/hip_runtime.h>

// TensorProduct: out[z, o*U+u] = sum_{p: idx_out[p]==o} coeffs[p] * x0[z, idx0[p]*U+u] * x1[z, idx1[p]*U+u]
// Z=16384, U=128, NSEG=(32,8,32), P=128, all f32. Measured HBM ~436 MB.
// Structure history: persistent dbuf (R5/R9) regressed; x1-from-global (R10) regressed;
// R8 one-shot all-LDS = 109 us with occupancy 72%, LDS ~60%, HBM 63% -> overlap-limited.
// R11 = R8 with BLK=256: 4 waves/block -> 8 blocks/CU (32 waves, 100% occupancy),
// 8 staggered stages per CU. Wave = 8 segments (4 per 32-lane half). Same inner loop.

#define Z_DIM 16384
#define U_DIM 128
#define NSEG0 32
#define NSEG1 8
#define NSEG2 32
#define P_DIM 128
#define BLK   256

#define X0_FLOATS (NSEG0 * U_DIM)   // 4096 floats (16 KB)
#define X1_FLOATS (NSEG1 * U_DIM)   // 1024 floats (4 KB)

// blob layout (ints): [0..32] seg offsets, [33..39] pad, [40..295] meta int2[128], [296..303] pad
#define META_BASE 40
#define BLOB_INTS 304                // 1216 B = 76 * 16 B

typedef float f32x4 __attribute__((ext_vector_type(4)));

// ---------- setup: group the P terms by output segment into the ws blob ----------
__global__ __launch_bounds__(128) void tp_setup(
    const float* __restrict__ coeffs,
    const int* __restrict__ idx0,
    const int* __restrict__ idx1,
    const int* __restrict__ idx_out,
    int* __restrict__ blob)
{
    __shared__ int s_cnt[NSEG2];
    __shared__ int s_off[NSEG2 + 1];
    const int t = threadIdx.x;            // exactly P_DIM threads
    if (t < NSEG2) s_cnt[t] = 0;
    __syncthreads();
    const int o = idx_out[t];
    const int r = atomicAdd(&s_cnt[o], 1);
    __syncthreads();
    if (t == 0) {
        int sum = 0;
        for (int i = 0; i < NSEG2; ++i) { s_off[i] = sum; sum += s_cnt[i]; }
        s_off[NSEG2] = sum;
    }
    __syncthreads();
    // byte offsets within a z-slice: i0*512 <= 15872, i1*512 <= 3584 (fit 16b each)
    const int d = s_off[o] + r;
    int2* meta = reinterpret_cast<int2*>(blob + META_BASE);
    meta[d] = make_int2((idx0[t] * (U_DIM * 4)) | ((idx1[t] * (U_DIM * 4)) << 16),
                        __float_as_int(coeffs[t]));
    if (t <= NSEG2) blob[t] = s_off[t];
    if (t >= 33 && t < META_BASE) blob[t] = 0;                       // pad
    if (t >= 296 && t < BLOB_INTS) blob[t] = 0;                      // tail pad
}

// ---------- main: one z-row per block, 4 waves ----------
__global__ __launch_bounds__(BLK, 8) void tp_kernel(
    const float* __restrict__ x0,
    const float* __restrict__ x1,
    const int* __restrict__ blob_g,
    float* __restrict__ out)
{
    __shared__ float s_x0[X0_FLOATS];     // 16 KB
    __shared__ float s_x1[X1_FLOATS];     //  4 KB
    __shared__ int   s_blob[BLOB_INTS];   // ~1.2 KB  -> 21.2 KB total -> 8 blocks/CU (wave cap)

    const int t = threadIdx.x;
    const size_t z = (size_t)blockIdx.x;

    // --- stage x0/x1 row + blob: async global->LDS, linear, 16 B/lane ---
    {
        const float4* g0 = reinterpret_cast<const float4*>(x0 + z * (size_t)X0_FLOATS);
        const float4* g1 = reinterpret_cast<const float4*>(x1 + z * (size_t)X1_FLOATS);
        const float4* gb = reinterpret_cast<const float4*>(blob_g);
        float4* l0 = reinterpret_cast<float4*>(s_x0);
        float4* l1 = reinterpret_cast<float4*>(s_x1);
        float4* lb = reinterpret_cast<float4*>(s_blob);
        #pragma unroll
        for (int i = 0; i < (X0_FLOATS / 4) / BLK; ++i)   // 4 iters
            __builtin_amdgcn_global_load_lds(
                (const __attribute__((address_space(1))) void*)(g0 + i * BLK + t),
                (__attribute__((address_space(3))) void*)(l0 + i * BLK + t),
                16, 0, 0);
        // X1: 256 float4s, all 256 threads, 1 iter
        __builtin_amdgcn_global_load_lds(
            (const __attribute__((address_space(1))) void*)(g1 + t),
            (__attribute__((address_space(3))) void*)(l1 + t),
            16, 0, 0);
        if (t < BLOB_INTS / 4)                             // 76 lanes
            __builtin_amdgcn_global_load_lds(
                (const __attribute__((address_space(1))) void*)(gb + t),
                (__attribute__((address_space(3))) void*)(lb + t),
                16, 0, 0);
    }
    __syncthreads();   // drains vmcnt; LDS tile + blob ready

    // --- compute: 4 waves x 8 segments; each 32-lane half owns 4 segments ---
    const int w  = t >> 6;                // wave 0..3
    const int h  = (t >> 5) & 1;          // lane half
    const int uq = t & 31;                // float4 column

    const int seg0 = 8 * w + 4 * h;       // this half's first segment
    const char* x0base = reinterpret_cast<const char*>(s_x0 + uq * 4);
    const char* x1base = reinterpret_cast<const char*>(s_x1 + uq * 4);
    const int2* s_meta = reinterpret_cast<const int2*>(s_blob + META_BASE);
    float* orow = out + z * (NSEG2 * U_DIM) + uq * 4;

    int sb = s_blob[seg0];                // half-divergent bounds (2-valued), benign
    #pragma unroll
    for (int oo = 0; oo < 4; ++oo) {
        const int se = s_blob[seg0 + oo + 1];
        f32x4 acc = (f32x4)0.f;
        int2 mt = s_meta[sb];             // s_meta[128] is zeroed pad, in-bounds
        for (int k = sb; k < se; ++k) {
            const int2 mn = s_meta[k + 1];            // depth-1 meta prefetch
            const float c = __int_as_float(mt.y);
            const f32x4 a = *reinterpret_cast<const f32x4*>(x0base + (mt.x & 0xffff));
            const f32x4 v = *reinterpret_cast<const f32x4*>(x1base + ((unsigned)mt.x >> 16));
            acc += a * v * c;             // contracts to v_fma
            mt = mn;
        }
        __builtin_nontemporal_store(acc,
            reinterpret_cast<f32x4*>(orow + (seg0 + oo) * U_DIM));
        sb = se;
    }
}

extern "C" void kernel_launch(void* const* d_in, const int* in_sizes, int n_in,
                              void* d_out, int out_size, void* d_ws, size_t ws_size,
                              hipStream_t stream) {
    const float* x0      = (const float*)d_in[0];
    const float* x1      = (const float*)d_in[1];
    const float* coeffs  = (const float*)d_in[2];
    const int*   idx0    = (const int*)d_in[3];
    const int*   idx1    = (const int*)d_in[4];
    const int*   idx_out = (const int*)d_in[5];
    float* out = (float*)d_out;

    int* blob = (int*)d_ws;   // BLOB_INTS ints, 16B-aligned

    tp_setup<<<1, P_DIM, 0, stream>>>(coeffs, idx0, idx1, idx_out, blob);
    tp_kernel<<<Z_DIM, BLK, 0, stream>>>(x0, x1, blob, out);
}